// Round 1
// baseline (2480.201 us; speedup 1.0000x reference)
//
#include <hip/hip_runtime.h>
#include <math.h>

#define N_ATOMS 50000
#define N_EDGES 800000
#define F 64
#define Z 192
#define NCONV 3
#define T_TGT 4096
#define EPS 1e-5f
#define SLOTS 64
#define SCAN_CH 256
#define NB_SCAN ((N_ATOMS + SCAN_CH - 1) / SCAN_CH)  // 196
#define TM 64
#define KB 32

static_assert(N_EDGES % TM == 0, "edge tiles exact");
static_assert(N_ATOMS % 4 == 0, "node waves exact");

static __device__ __forceinline__ float bf2f(unsigned short u) {
    return __uint_as_float(((unsigned int)u) << 16);
}
static __device__ __forceinline__ unsigned short f2bf(float f) {
    unsigned int u = __float_as_uint(f);
    unsigned int r = u + 0x7FFFu + ((u >> 16) & 1u);
    return (unsigned short)(r >> 16);
}

// ---------------- preprocessing ----------------

__global__ void k_embed(const int* __restrict__ types, const float* __restrict__ emb,
                        float* __restrict__ x) {
    int idx = blockIdx.x * 256 + threadIdx.x;
    if (idx < N_ATOMS * F) {
        int n = idx >> 6, f = idx & 63;
        x[idx] = emb[types[n] * F + f];
    }
}

__global__ void k_degree(const int* __restrict__ idx_i, int* __restrict__ cnt) {
    int e = blockIdx.x * 256 + threadIdx.x;
    if (e < N_EDGES) atomicAdd(&cnt[idx_i[e]], 1);
}

__global__ void k_scanA(const int* __restrict__ cnt, int* __restrict__ bsum) {
    __shared__ int s[256];
    int base = blockIdx.x * 256, t = threadIdx.x;
    s[t] = (base + t < N_ATOMS) ? cnt[base + t] : 0;
    __syncthreads();
    for (int o = 128; o > 0; o >>= 1) {
        if (t < o) s[t] += s[t + o];
        __syncthreads();
    }
    if (t == 0) bsum[blockIdx.x] = s[0];
}

__global__ void k_scanB(int* __restrict__ bsum, int* __restrict__ rowptr) {
    __shared__ int s[256];
    int t = threadIdx.x;
    int v = (t < NB_SCAN) ? bsum[t] : 0;
    s[t] = v;
    __syncthreads();
    for (int o = 1; o < 256; o <<= 1) {
        int add = (t >= o) ? s[t - o] : 0;
        __syncthreads();
        s[t] += add;
        __syncthreads();
    }
    if (t < NB_SCAN) bsum[t] = s[t] - v;  // exclusive
    if (t == 0) rowptr[N_ATOMS] = N_EDGES;
}

__global__ void k_scanC(const int* __restrict__ cnt, const int* __restrict__ bsum,
                        int* __restrict__ rowptr) {
    __shared__ int s[256];
    int base = blockIdx.x * 256, t = threadIdx.x;
    int v = (base + t < N_ATOMS) ? cnt[base + t] : 0;
    s[t] = v;
    __syncthreads();
    for (int o = 1; o < 256; o <<= 1) {
        int add = (t >= o) ? s[t - o] : 0;
        __syncthreads();
        s[t] += add;
        __syncthreads();
    }
    if (base + t < N_ATOMS) rowptr[base + t] = bsum[blockIdx.x] + s[t] - v;
}

__global__ void k_scatter(const int* __restrict__ idx_i, const int* __restrict__ idx_j,
                          const int* __restrict__ rowptr, int* __restrict__ wofs,
                          int* __restrict__ i_s, int* __restrict__ j_s,
                          int* __restrict__ eperm) {
    int e = blockIdx.x * 256 + threadIdx.x;
    if (e < N_EDGES) {
        int i = idx_i[e];
        int pos = rowptr[i] + atomicAdd(&wofs[i], 1);
        i_s[pos] = i;
        j_s[pos] = idx_j[e];
        eperm[pos] = e;
    }
}

// ---------------- per-layer kernels ----------------

// Edge GEMM: y[e,0:64] = z @ Wc^T + bc (stored bf16), filt[e] = z . Wf + bf.
// Also accumulates per-feature sum/sumsq of y into slot-replicated stats.
__global__ __launch_bounds__(256) void k_edge_mm(
    const float* __restrict__ x,
    const int* __restrict__ i_s, const int* __restrict__ j_s, const int* __restrict__ eperm,
    const float* __restrict__ ea,
    const float* __restrict__ Wc, const float* __restrict__ bc,
    const float* __restrict__ Wf, const float* __restrict__ bfp,
    unsigned short* __restrict__ y, float* __restrict__ filt,
    float* __restrict__ stats)
{
    __shared__ float A[KB][68];   // A[k][m] (pad 68 to stagger banks, keeps 16B align)
    __shared__ float B[KB][64];   // B[k][n] = Wc[n][kc+k]
    __shared__ float Wfs[KB];
    int t = threadIdx.x;
    int e0 = blockIdx.x * TM;
    int tx = t & 15, ty = t >> 4;        // compute mapping: 4x4 micro-tile
    int ms = t & 63;                     // staging: edge within tile
    int kk = (t >> 6) * 8;               // staging: k sub-offset
    int em = e0 + ms;
    const float* rowi = x + (size_t)i_s[em] * F;
    const float* rowj = x + (size_t)j_s[em] * F;
    const float* rowe = ea + (size_t)eperm[em] * F;
    int nB = t >> 2;                     // B staging: feature row 0..63
    int kB = (t & 3) * 8;                // B staging: k sub-offset
    float acc[4][4] = {{0.f}};
    float facc = 0.f;

    for (int kc = 0; kc < Z; kc += KB) {
        const float* src = (kc < F) ? (rowi + kc)
                         : (kc < 2 * F) ? (rowj + (kc - F))
                                        : (rowe + (kc - 2 * F));
        float4 a0 = *(const float4*)(src + kk);
        float4 a1 = *(const float4*)(src + kk + 4);
        const float* wsrc = Wc + (size_t)nB * Z + kc + kB;
        float4 b0 = *(const float4*)(wsrc);
        float4 b1 = *(const float4*)(wsrc + 4);
        __syncthreads();   // previous chunk's compute done before overwrite
        A[kk + 0][ms] = a0.x; A[kk + 1][ms] = a0.y; A[kk + 2][ms] = a0.z; A[kk + 3][ms] = a0.w;
        A[kk + 4][ms] = a1.x; A[kk + 5][ms] = a1.y; A[kk + 6][ms] = a1.z; A[kk + 7][ms] = a1.w;
        B[kB + 0][nB] = b0.x; B[kB + 1][nB] = b0.y; B[kB + 2][nB] = b0.z; B[kB + 3][nB] = b0.w;
        B[kB + 4][nB] = b1.x; B[kB + 5][nB] = b1.y; B[kB + 6][nB] = b1.z; B[kB + 7][nB] = b1.w;
        if (t < KB) Wfs[t] = Wf[kc + t];
        __syncthreads();
        #pragma unroll
        for (int k = 0; k < KB; ++k) {
            float4 av = *(const float4*)&A[k][ty * 4];
            float4 bv = *(const float4*)&B[k][tx * 4];
            acc[0][0] += av.x * bv.x; acc[0][1] += av.x * bv.y; acc[0][2] += av.x * bv.z; acc[0][3] += av.x * bv.w;
            acc[1][0] += av.y * bv.x; acc[1][1] += av.y * bv.y; acc[1][2] += av.y * bv.z; acc[1][3] += av.y * bv.w;
            acc[2][0] += av.z * bv.x; acc[2][1] += av.z * bv.y; acc[2][2] += av.z * bv.z; acc[2][3] += av.z * bv.w;
            acc[3][0] += av.w * bv.x; acc[3][1] += av.w * bv.y; acc[3][2] += av.w * bv.z; acc[3][3] += av.w * bv.w;
        }
        if (t < TM) {   // wave 0 only: filt dot-product (wave-uniform branch)
            #pragma unroll
            for (int k = 0; k < KB; ++k) facc += A[k][t] * Wfs[k];
        }
    }

    float bcv[4];
    #pragma unroll
    for (int c = 0; c < 4; ++c) bcv[c] = bc[tx * 4 + c];

    // write y (bf16, 8B packed stores)
    #pragma unroll
    for (int mm = 0; mm < 4; ++mm) {
        unsigned int w0 = (unsigned int)f2bf(acc[mm][0] + bcv[0]) |
                          ((unsigned int)f2bf(acc[mm][1] + bcv[1]) << 16);
        unsigned int w1 = (unsigned int)f2bf(acc[mm][2] + bcv[2]) |
                          ((unsigned int)f2bf(acc[mm][3] + bcv[3]) << 16);
        uint2 pk; pk.x = w0; pk.y = w1;
        *(uint2*)&y[(size_t)(e0 + ty * 4 + mm) * F + tx * 4] = pk;
    }
    if (t < TM) filt[e0 + t] = facc + bfp[0];

    // BN1 stats: block reduce (reuse B), then slot-replicated atomics
    float* sbuf = &B[0][0];   // 2048 floats available
    int slot = (blockIdx.x & (SLOTS - 1)) * 128;
    __syncthreads();
    #pragma unroll
    for (int c = 0; c < 4; ++c) {
        float s = 0.f;
        #pragma unroll
        for (int mm = 0; mm < 4; ++mm) s += acc[mm][c] + bcv[c];
        sbuf[ty * 64 + tx * 4 + c] = s;
    }
    __syncthreads();
    if (t < F) {
        float S = 0.f;
        #pragma unroll
        for (int g = 0; g < 16; ++g) S += sbuf[g * 64 + t];
        atomicAdd(&stats[slot + t], S);
    }
    __syncthreads();
    #pragma unroll
    for (int c = 0; c < 4; ++c) {
        float q = 0.f;
        #pragma unroll
        for (int mm = 0; mm < 4; ++mm) {
            float v = acc[mm][c] + bcv[c];
            q += v * v;
        }
        sbuf[ty * 64 + tx * 4 + c] = q;
    }
    __syncthreads();
    if (t < F) {
        float Q = 0.f;
        #pragma unroll
        for (int g = 0; g < 16; ++g) Q += sbuf[g * 64 + t];
        atomicAdd(&stats[slot + 64 + t], Q);
    }
}

__global__ void k_finbn(const float* __restrict__ stats, float* __restrict__ bnp, float count) {
    int f = threadIdx.x;  // 64 threads
    float S = 0.f, Q = 0.f;
    for (int s = 0; s < SLOTS; ++s) {
        S += stats[s * 128 + f];
        Q += stats[s * 128 + 64 + f];
    }
    float mu = S / count;
    float var = Q / count - mu * mu;
    var = fmaxf(var, 0.f);
    bnp[f] = mu;
    bnp[64 + f] = 1.f / sqrtf(var + EPS);
}

// One wave per node: segment max -> exp weights -> BN1+ReLU core weighted sum.
__global__ __launch_bounds__(256) void k_node_agg(
    const unsigned short* __restrict__ y, const float* __restrict__ filt,
    const int* __restrict__ rowptr, const int* __restrict__ cnt,
    const float* __restrict__ bnp, const float* __restrict__ g1, const float* __restrict__ b1,
    float* __restrict__ agg)
{
    int t = threadIdx.x;
    int lane = t & 63;
    int node = blockIdx.x * 4 + (t >> 6);
    if (node >= N_ATOMS) return;
    int beg = rowptr[node], end = rowptr[node + 1];
    float mu = bnp[lane], rstd = bnp[64 + lane];
    float ga = g1[lane], be = b1[lane];
    float fm = -INFINITY;
    for (int i = beg + lane; i < end; i += 64) fm = fmaxf(fm, filt[i]);
    #pragma unroll
    for (int o = 32; o > 0; o >>= 1) fm = fmaxf(fm, __shfl_xor(fm, o, 64));
    float acc = 0.f, ssum = 0.f;
    for (int e = beg; e < end; ++e) {
        float w = expf(filt[e] - fm);
        float yv = bf2f(y[(size_t)e * F + lane]);
        float core = fmaxf((yv - mu) * rstd * ga + be, 0.f);
        acc += w * core;
        ssum += w;
    }
    float dn = fmaxf((float)cnt[node], 1.f);
    agg[(size_t)node * F + lane] = acc / (ssum + 1e-16f) / dn;
}

__global__ void k_colstats(const float* __restrict__ agg, float* __restrict__ stats) {
    __shared__ float buf[4][64];
    int t = threadIdx.x;
    int f = t & 63, g = t >> 6;
    float S = 0.f, Q = 0.f;
    for (int n = blockIdx.x * 4 + g; n < N_ATOMS; n += gridDim.x * 4) {
        float v = agg[(size_t)n * F + f];
        S += v; Q += v * v;
    }
    buf[g][f] = S;
    __syncthreads();
    if (t < 64) {
        float s2 = buf[0][t] + buf[1][t] + buf[2][t] + buf[3][t];
        atomicAdd(&stats[(blockIdx.x & 63) * 128 + t], s2);
    }
    __syncthreads();
    buf[g][f] = Q;
    __syncthreads();
    if (t < 64) {
        float q2 = buf[0][t] + buf[1][t] + buf[2][t] + buf[3][t];
        atomicAdd(&stats[(blockIdx.x & 63) * 128 + 64 + t], q2);
    }
}

__global__ void k_node_upd(const float* __restrict__ agg, const float* __restrict__ bnp,
                           const float* __restrict__ g2, const float* __restrict__ b2,
                           const float* __restrict__ xin, float* __restrict__ xout) {
    int idx = blockIdx.x * 256 + threadIdx.x;
    if (idx < N_ATOMS * F) {
        int f = idx & 63;
        float v = (agg[idx] - bnp[f]) * bnp[64 + f] * g2[f] + b2[f] + xin[idx];
        xout[idx] = fmaxf(v, 0.f);
    }
}

// ---------------- head ----------------

__global__ __launch_bounds__(256) void k_head(
    const float* __restrict__ x, const int* __restrict__ target,
    const float* __restrict__ Wfc, const float* __restrict__ bfc,
    const float* __restrict__ Ws, const float* __restrict__ bs,
    float* __restrict__ out)
{
    __shared__ float hbuf[4][64];
    int t = threadIdx.x;
    int lane = t & 63, w = t >> 6;
    int tt = blockIdx.x * 4 + w;
    int a = target[min(tt, T_TGT - 1)];
    float h = fmaxf(x[(size_t)a * F + lane], 0.f);
    hbuf[w][lane] = h;
    __syncthreads();
    float acc = bfc[lane];
    #pragma unroll 8
    for (int k = 0; k < F; ++k) acc += hbuf[w][k] * Wfc[lane * F + k];
    float h2 = fmaxf(acc, 0.f);
    float p0 = h2 * Ws[lane];
    float p1 = h2 * Ws[F + lane];
    #pragma unroll
    for (int o = 32; o > 0; o >>= 1) {
        p0 += __shfl_xor(p0, o, 64);
        p1 += __shfl_xor(p1, o, 64);
    }
    if (lane == 0 && tt < T_TGT) {
        float l0 = p0 + bs[0], l1 = p1 + bs[1];
        float mx = fmaxf(l0, l1);
        float e0v = expf(l0 - mx), e1v = expf(l1 - mx);
        float inv = 1.f / (e0v + e1v);
        out[tt * 2 + 0] = e0v * inv;
        out[tt * 2 + 1] = e1v * inv;
    }
}

// ---------------- launch ----------------

extern "C" void kernel_launch(void* const* d_in, const int* in_sizes, int n_in,
                              void* d_out, int out_size, void* d_ws, size_t ws_size,
                              hipStream_t stream)
{
    const int*   x_types = (const int*)d_in[0];
    const int*   eidx    = (const int*)d_in[1];
    const float* ea      = (const float*)d_in[2];
    const int*   target  = (const int*)d_in[3];
    const float* emb     = (const float*)d_in[4];
    const float* Wc      = (const float*)d_in[5];
    const float* bc      = (const float*)d_in[6];
    const float* Wf      = (const float*)d_in[7];
    const float* bfp     = (const float*)d_in[8];
    const float* g1      = (const float*)d_in[9];
    const float* b1      = (const float*)d_in[10];
    const float* g2      = (const float*)d_in[11];
    const float* b2      = (const float*)d_in[12];
    const float* Wfc     = (const float*)d_in[13];
    const float* bfc     = (const float*)d_in[14];
    const float* Ws      = (const float*)d_in[15];
    const float* bs      = (const float*)d_in[16];
    float* out = (float*)d_out;
    const int* idx_i = eidx;
    const int* idx_j = eidx + N_EDGES;

    char* p = (char*)d_ws;
    auto alloc = [&](size_t bytes) {
        char* r = p;
        p += (bytes + 255) & ~(size_t)255;
        return r;
    };
    float* xa            = (float*)alloc((size_t)N_ATOMS * F * 4);
    float* xb            = (float*)alloc((size_t)N_ATOMS * F * 4);
    unsigned short* ybuf = (unsigned short*)alloc((size_t)N_EDGES * F * 2);
    float* filt          = (float*)alloc((size_t)N_EDGES * 4);
    float* agg           = (float*)alloc((size_t)N_ATOMS * F * 4);
    int* cnt             = (int*)alloc((size_t)N_ATOMS * 4);
    int* rowptr          = (int*)alloc((size_t)(N_ATOMS + 1) * 4);
    int* wofs            = (int*)alloc((size_t)N_ATOMS * 4);
    int* i_s             = (int*)alloc((size_t)N_EDGES * 4);
    int* j_s             = (int*)alloc((size_t)N_EDGES * 4);
    int* eperm           = (int*)alloc((size_t)N_EDGES * 4);
    int* bsum            = (int*)alloc(256 * 4);
    float* stats         = (float*)alloc(SLOTS * 128 * 4);
    float* bnp1          = (float*)alloc(128 * 4);
    float* bnp2          = (float*)alloc(128 * 4);
    (void)ws_size; (void)in_sizes; (void)n_in; (void)out_size;

    hipMemsetAsync(cnt, 0, (size_t)N_ATOMS * 4, stream);
    hipMemsetAsync(wofs, 0, (size_t)N_ATOMS * 4, stream);
    k_embed<<<(N_ATOMS * F + 255) / 256, 256, 0, stream>>>(x_types, emb, xa);
    k_degree<<<(N_EDGES + 255) / 256, 256, 0, stream>>>(idx_i, cnt);
    k_scanA<<<NB_SCAN, 256, 0, stream>>>(cnt, bsum);
    k_scanB<<<1, 256, 0, stream>>>(bsum, rowptr);
    k_scanC<<<NB_SCAN, 256, 0, stream>>>(cnt, bsum, rowptr);
    k_scatter<<<(N_EDGES + 255) / 256, 256, 0, stream>>>(idx_i, idx_j, rowptr, wofs,
                                                         i_s, j_s, eperm);

    float* xcur = xa;
    float* xnxt = xb;
    for (int l = 0; l < NCONV; ++l) {
        hipMemsetAsync(stats, 0, SLOTS * 128 * 4, stream);
        k_edge_mm<<<N_EDGES / TM, 256, 0, stream>>>(
            xcur, i_s, j_s, eperm, ea,
            Wc + (size_t)l * F * Z, bc + (size_t)l * F,
            Wf + (size_t)l * Z, bfp + l,
            ybuf, filt, stats);
        k_finbn<<<1, 64, 0, stream>>>(stats, bnp1, (float)N_EDGES);
        k_node_agg<<<N_ATOMS / 4, 256, 0, stream>>>(ybuf, filt, rowptr, cnt, bnp1,
                                                    g1 + (size_t)l * F, b1 + (size_t)l * F, agg);
        hipMemsetAsync(stats, 0, SLOTS * 128 * 4, stream);
        k_colstats<<<256, 256, 0, stream>>>(agg, stats);
        k_finbn<<<1, 64, 0, stream>>>(stats, bnp2, (float)N_ATOMS);
        k_node_upd<<<(N_ATOMS * F + 255) / 256, 256, 0, stream>>>(
            agg, bnp2, g2 + (size_t)l * F, b2 + (size_t)l * F, xcur, xnxt);
        float* tmp = xcur; xcur = xnxt; xnxt = tmp;
    }
    k_head<<<T_TGT / 4, 256, 0, stream>>>(xcur, target, Wfc, bfc, Ws, bs, out);
}

// Round 2
// 858.859 us; speedup vs baseline: 2.8878x; 2.8878x over previous
//
#include <hip/hip_runtime.h>
#include <math.h>

#define N_ATOMS 50000
#define N_EDGES 800000
#define F 64
#define Z 192
#define NCONV 3
#define T_TGT 4096
#define EPS 1e-5f
#define SLOTS 64
#define NB_SCAN 196          // ceil(50000/256)
#define TILE_E 128
#define TPB_TILES 5
#define NBLK_MM 1250         // 1250*5*128 = 800000

typedef __attribute__((ext_vector_type(4))) float f32x4;
typedef __attribute__((ext_vector_type(8))) short s16x8;
typedef __attribute__((ext_vector_type(8))) __bf16 bf16x8;

static_assert(NBLK_MM * TPB_TILES * TILE_E == N_EDGES, "tiling exact");

static __device__ __forceinline__ float bf2f(unsigned short u) {
    return __uint_as_float(((unsigned int)u) << 16);
}
static __device__ __forceinline__ unsigned short f2bf(float f) {
    unsigned int u = __float_as_uint(f);
    unsigned int r = u + 0x7FFFu + ((u >> 16) & 1u);
    return (unsigned short)(r >> 16);
}
static __device__ __forceinline__ bf16x8 pack8(float4 a, float4 b) {
    s16x8 r;
    r[0] = (short)f2bf(a.x); r[1] = (short)f2bf(a.y);
    r[2] = (short)f2bf(a.z); r[3] = (short)f2bf(a.w);
    r[4] = (short)f2bf(b.x); r[5] = (short)f2bf(b.y);
    r[6] = (short)f2bf(b.z); r[7] = (short)f2bf(b.w);
    return __builtin_bit_cast(bf16x8, r);
}

// ---------------- preprocessing ----------------

__global__ void k_embed(const int* __restrict__ types, const float* __restrict__ emb,
                        float* __restrict__ x, unsigned short* __restrict__ xb) {
    int idx = blockIdx.x * 256 + threadIdx.x;
    if (idx < N_ATOMS * F) {
        int n = idx >> 6, f = idx & 63;
        float v = emb[types[n] * F + f];
        x[idx] = v;
        xb[idx] = f2bf(v);
    }
}

__global__ void k_degree(const int* __restrict__ idx_i, int* __restrict__ cnt) {
    int e = blockIdx.x * 256 + threadIdx.x;
    if (e < N_EDGES) atomicAdd(&cnt[idx_i[e]], 1);
}

__global__ void k_scanA(const int* __restrict__ cnt, int* __restrict__ bsum) {
    __shared__ int s[256];
    int base = blockIdx.x * 256, t = threadIdx.x;
    s[t] = (base + t < N_ATOMS) ? cnt[base + t] : 0;
    __syncthreads();
    for (int o = 128; o > 0; o >>= 1) {
        if (t < o) s[t] += s[t + o];
        __syncthreads();
    }
    if (t == 0) bsum[blockIdx.x] = s[0];
}

__global__ void k_scanB(int* __restrict__ bsum, int* __restrict__ rowptr) {
    __shared__ int s[256];
    int t = threadIdx.x;
    int v = (t < NB_SCAN) ? bsum[t] : 0;
    s[t] = v;
    __syncthreads();
    for (int o = 1; o < 256; o <<= 1) {
        int add = (t >= o) ? s[t - o] : 0;
        __syncthreads();
        s[t] += add;
        __syncthreads();
    }
    if (t < NB_SCAN) bsum[t] = s[t] - v;  // exclusive
    if (t == 0) rowptr[N_ATOMS] = N_EDGES;
}

__global__ void k_scanC(const int* __restrict__ cnt, const int* __restrict__ bsum,
                        int* __restrict__ rowptr) {
    __shared__ int s[256];
    int base = blockIdx.x * 256, t = threadIdx.x;
    int v = (base + t < N_ATOMS) ? cnt[base + t] : 0;
    s[t] = v;
    __syncthreads();
    for (int o = 1; o < 256; o <<= 1) {
        int add = (t >= o) ? s[t - o] : 0;
        __syncthreads();
        s[t] += add;
        __syncthreads();
    }
    if (base + t < N_ATOMS) rowptr[base + t] = bsum[blockIdx.x] + s[t] - v;
}

__global__ void k_scatter(const int* __restrict__ idx_i, const int* __restrict__ idx_j,
                          const int* __restrict__ rowptr, int* __restrict__ wofs,
                          int* __restrict__ i_s, int* __restrict__ j_s,
                          int* __restrict__ eperm) {
    int e = blockIdx.x * 256 + threadIdx.x;
    if (e < N_EDGES) {
        int i = idx_i[e];
        int pos = rowptr[i] + atomicAdd(&wofs[i], 1);
        i_s[pos] = i;
        j_s[pos] = idx_j[e];
        eperm[pos] = e;
    }
}

// edge_attr -> bf16, permuted into CSR order (sequential reads in edge GEMM)
__global__ void k_ea_cvt(const float* __restrict__ ea, const int* __restrict__ eperm,
                         unsigned short* __restrict__ eab) {
    int idx = blockIdx.x * 256 + threadIdx.x;   // one thread per 8 elements
    int row = idx >> 3;
    int seg = (idx & 7) * 8;
    if (row < N_EDGES) {
        const float* src = ea + (size_t)eperm[row] * F + seg;
        float4 a = *(const float4*)src;
        float4 b = *(const float4*)(src + 4);
        bf16x8 r = pack8(a, b);
        *(bf16x8*)(eab + (size_t)row * F + seg) = r;
    }
}

// ---------------- edge GEMM (MFMA) ----------------
// y[e,0:64] = z @ Wc^T (bf16 out, bias dropped: cancels in BN)
// filt[e]   = z . Wf   (bias dropped: cancels in segment softmax)
// stats: per-feature sum / sumsq of y (fp32, pre-rounding)
__global__ __launch_bounds__(256, 2) void k_edge_mfma(
    const unsigned short* __restrict__ xb, const unsigned short* __restrict__ eab,
    const int* __restrict__ i_s, const int* __restrict__ j_s,
    const float* __restrict__ Wc, const float* __restrict__ Wf,
    unsigned short* __restrict__ y, float* __restrict__ filt,
    float* __restrict__ stats)
{
    int t = threadIdx.x;
    int lane = t & 63, w = t >> 6;
    int c = lane & 15, g = lane >> 4;
    int goff = g * 8;

    // B fragments: Wc rows (cols of B), plus filt column tile (nt=4)
    bf16x8 Bf[6][5];
    #pragma unroll
    for (int nt = 0; nt < 4; ++nt) {
        const float* wrow = Wc + (size_t)(nt * 16 + c) * Z;
        #pragma unroll
        for (int kt = 0; kt < 6; ++kt) {
            const float* wp = wrow + kt * 32 + goff;
            float4 w0 = *(const float4*)wp;
            float4 w1 = *(const float4*)(wp + 4);
            Bf[kt][nt] = pack8(w0, w1);
        }
    }
    #pragma unroll
    for (int kt = 0; kt < 6; ++kt) {
        s16x8 zz = {0, 0, 0, 0, 0, 0, 0, 0};
        bf16x8 r = __builtin_bit_cast(bf16x8, zz);
        if (c == 0) {
            const float* wp = Wf + kt * 32 + goff;
            float4 w0 = *(const float4*)wp;
            float4 w1 = *(const float4*)(wp + 4);
            r = pack8(w0, w1);
        }
        Bf[kt][4] = r;
    }

    int tile = blockIdx.x * TPB_TILES;

    // prologue: A fragments for first tile (direct per-lane global gather)
    bf16x8 Af[2][6];
    #pragma unroll
    for (int m = 0; m < 2; ++m) {
        int e = tile * TILE_E + (w * 2 + m) * 16 + c;
        const unsigned short* bi = xb + (size_t)i_s[e] * F + goff;
        const unsigned short* bj = xb + (size_t)j_s[e] * F + goff;
        const unsigned short* be = eab + (size_t)e * F + goff;
        Af[m][0] = *(const bf16x8*)(bi);
        Af[m][1] = *(const bf16x8*)(bi + 32);
        Af[m][2] = *(const bf16x8*)(bj);
        Af[m][3] = *(const bf16x8*)(bj + 32);
        Af[m][4] = *(const bf16x8*)(be);
        Af[m][5] = *(const bf16x8*)(be + 32);
    }

    float ssum[4] = {0.f, 0.f, 0.f, 0.f};
    float ssq[4]  = {0.f, 0.f, 0.f, 0.f};

    for (int it = 0; it < TPB_TILES; ++it) {
        int cur = tile + it;
        int nxt = (it + 1 < TPB_TILES) ? cur + 1 : cur;
        const unsigned short *bi2[2], *bj2[2], *be2[2];
        #pragma unroll
        for (int m = 0; m < 2; ++m) {
            int e = nxt * TILE_E + (w * 2 + m) * 16 + c;
            bi2[m] = xb + (size_t)i_s[e] * F + goff;
            bj2[m] = xb + (size_t)j_s[e] * F + goff;
            be2[m] = eab + (size_t)e * F + goff;
        }

        f32x4 acc[2][5];
        #pragma unroll
        for (int m = 0; m < 2; ++m)
            #pragma unroll
            for (int nt = 0; nt < 5; ++nt)
                acc[m][nt] = (f32x4){0.f, 0.f, 0.f, 0.f};

        #pragma unroll
        for (int kt = 0; kt < 6; ++kt) {
            #pragma unroll
            for (int m = 0; m < 2; ++m) {
                #pragma unroll
                for (int nt = 0; nt < 5; ++nt)
                    acc[m][nt] = __builtin_amdgcn_mfma_f32_16x16x32_bf16(
                        Af[m][kt], Bf[kt][nt], acc[m][nt], 0, 0, 0);
            }
            // prefetch next tile's fragment kt (latency hidden by remaining MFMAs)
            #pragma unroll
            for (int m = 0; m < 2; ++m) {
                const unsigned short* p = (kt < 2) ? bi2[m] : (kt < 4) ? bj2[m] : be2[m];
                Af[m][kt] = *(const bf16x8*)(p + (kt & 1) * 32);
            }
        }

        // epilogue: y store (bf16), filt store, stats accumulate in regs
        #pragma unroll
        for (int m = 0; m < 2; ++m) {
            int ebase = cur * TILE_E + (w * 2 + m) * 16 + g * 4;
            #pragma unroll
            for (int nt = 0; nt < 4; ++nt) {
                #pragma unroll
                for (int q = 0; q < 4; ++q) {
                    float v = acc[m][nt][q];
                    y[(size_t)(ebase + q) * F + nt * 16 + c] = f2bf(v);
                    ssum[nt] += v;
                    ssq[nt] += v * v;
                }
            }
            if (c == 0) {
                #pragma unroll
                for (int q = 0; q < 4; ++q) filt[ebase + q] = acc[m][4][q];
            }
        }
    }

    // stats: reduce lane-groups (same col c across g=0..3), one atomic per col
    int slot = (blockIdx.x & (SLOTS - 1)) * 128;
    #pragma unroll
    for (int nt = 0; nt < 4; ++nt) {
        float S = ssum[nt], Q = ssq[nt];
        S += __shfl_xor(S, 16, 64); S += __shfl_xor(S, 32, 64);
        Q += __shfl_xor(Q, 16, 64); Q += __shfl_xor(Q, 32, 64);
        if (g == 0) {
            atomicAdd(&stats[slot + nt * 16 + c], S);
            atomicAdd(&stats[slot + 64 + nt * 16 + c], Q);
        }
    }
}

// ---------------- per-layer small kernels ----------------

__global__ void k_finbn(const float* __restrict__ stats, float* __restrict__ bnp, float count) {
    int f = threadIdx.x;  // 64 threads
    float S = 0.f, Q = 0.f;
    for (int s = 0; s < SLOTS; ++s) {
        S += stats[s * 128 + f];
        Q += stats[s * 128 + 64 + f];
    }
    float mu = S / count;
    float var = Q / count - mu * mu;
    var = fmaxf(var, 0.f);
    bnp[f] = mu;
    bnp[64 + f] = 1.f / sqrtf(var + EPS);
}

__global__ __launch_bounds__(256) void k_node_agg(
    const unsigned short* __restrict__ y, const float* __restrict__ filt,
    const int* __restrict__ rowptr, const int* __restrict__ cnt,
    const float* __restrict__ bnp, const float* __restrict__ g1, const float* __restrict__ b1,
    float* __restrict__ agg)
{
    int t = threadIdx.x;
    int lane = t & 63;
    int node = blockIdx.x * 4 + (t >> 6);
    if (node >= N_ATOMS) return;
    int beg = rowptr[node], end = rowptr[node + 1];
    float mu = bnp[lane], rstd = bnp[64 + lane];
    float ga = g1[lane], be = b1[lane];
    float fm = -INFINITY;
    for (int i = beg + lane; i < end; i += 64) fm = fmaxf(fm, filt[i]);
    #pragma unroll
    for (int o = 32; o > 0; o >>= 1) fm = fmaxf(fm, __shfl_xor(fm, o, 64));
    float acc = 0.f, ssum = 0.f;
    for (int e = beg; e < end; ++e) {
        float wgt = expf(filt[e] - fm);
        float yv = bf2f(y[(size_t)e * F + lane]);
        float core = fmaxf((yv - mu) * rstd * ga + be, 0.f);
        acc += wgt * core;
        ssum += wgt;
    }
    float dn = fmaxf((float)cnt[node], 1.f);
    agg[(size_t)node * F + lane] = acc / (ssum + 1e-16f) / dn;
}

__global__ void k_colstats(const float* __restrict__ agg, float* __restrict__ stats) {
    __shared__ float buf[4][64];
    int t = threadIdx.x;
    int f = t & 63, g = t >> 6;
    float S = 0.f, Q = 0.f;
    for (int n = blockIdx.x * 4 + g; n < N_ATOMS; n += gridDim.x * 4) {
        float v = agg[(size_t)n * F + f];
        S += v; Q += v * v;
    }
    buf[g][f] = S;
    __syncthreads();
    if (t < 64) {
        float s2 = buf[0][t] + buf[1][t] + buf[2][t] + buf[3][t];
        atomicAdd(&stats[(blockIdx.x & 63) * 128 + t], s2);
    }
    __syncthreads();
    buf[g][f] = Q;
    __syncthreads();
    if (t < 64) {
        float q2 = buf[0][t] + buf[1][t] + buf[2][t] + buf[3][t];
        atomicAdd(&stats[(blockIdx.x & 63) * 128 + 64 + t], q2);
    }
}

__global__ void k_node_upd(const float* __restrict__ agg, const float* __restrict__ bnp,
                           const float* __restrict__ g2, const float* __restrict__ b2,
                           const float* __restrict__ xin, float* __restrict__ xout,
                           unsigned short* __restrict__ xbout) {
    int idx = blockIdx.x * 256 + threadIdx.x;
    if (idx < N_ATOMS * F) {
        int f = idx & 63;
        float v = (agg[idx] - bnp[f]) * bnp[64 + f] * g2[f] + b2[f] + xin[idx];
        v = fmaxf(v, 0.f);
        xout[idx] = v;
        xbout[idx] = f2bf(v);
    }
}

// ---------------- head ----------------

__global__ __launch_bounds__(256) void k_head(
    const float* __restrict__ x, const int* __restrict__ target,
    const float* __restrict__ Wfc, const float* __restrict__ bfc,
    const float* __restrict__ Ws, const float* __restrict__ bs,
    float* __restrict__ out)
{
    __shared__ float hbuf[4][64];
    int t = threadIdx.x;
    int lane = t & 63, w = t >> 6;
    int tt = blockIdx.x * 4 + w;
    int a = target[min(tt, T_TGT - 1)];
    float h = fmaxf(x[(size_t)a * F + lane], 0.f);
    hbuf[w][lane] = h;
    __syncthreads();
    float acc = bfc[lane];
    #pragma unroll 8
    for (int k = 0; k < F; ++k) acc += hbuf[w][k] * Wfc[lane * F + k];
    float h2 = fmaxf(acc, 0.f);
    float p0 = h2 * Ws[lane];
    float p1 = h2 * Ws[F + lane];
    #pragma unroll
    for (int o = 32; o > 0; o >>= 1) {
        p0 += __shfl_xor(p0, o, 64);
        p1 += __shfl_xor(p1, o, 64);
    }
    if (lane == 0 && tt < T_TGT) {
        float l0 = p0 + bs[0], l1 = p1 + bs[1];
        float mx = fmaxf(l0, l1);
        float e0v = expf(l0 - mx), e1v = expf(l1 - mx);
        float inv = 1.f / (e0v + e1v);
        out[tt * 2 + 0] = e0v * inv;
        out[tt * 2 + 1] = e1v * inv;
    }
}

// ---------------- launch ----------------

extern "C" void kernel_launch(void* const* d_in, const int* in_sizes, int n_in,
                              void* d_out, int out_size, void* d_ws, size_t ws_size,
                              hipStream_t stream)
{
    const int*   x_types = (const int*)d_in[0];
    const int*   eidx    = (const int*)d_in[1];
    const float* ea      = (const float*)d_in[2];
    const int*   target  = (const int*)d_in[3];
    const float* emb     = (const float*)d_in[4];
    const float* Wc      = (const float*)d_in[5];
    const float* Wf      = (const float*)d_in[7];
    const float* g1      = (const float*)d_in[9];
    const float* b1      = (const float*)d_in[10];
    const float* g2      = (const float*)d_in[11];
    const float* b2      = (const float*)d_in[12];
    const float* Wfc     = (const float*)d_in[13];
    const float* bfc     = (const float*)d_in[14];
    const float* Ws      = (const float*)d_in[15];
    const float* bs      = (const float*)d_in[16];
    float* out = (float*)d_out;
    const int* idx_i = eidx;
    const int* idx_j = eidx + N_EDGES;

    char* p = (char*)d_ws;
    auto alloc = [&](size_t bytes) {
        char* r = p;
        p += (bytes + 255) & ~(size_t)255;
        return r;
    };
    float* xa            = (float*)alloc((size_t)N_ATOMS * F * 4);
    float* xb_f          = (float*)alloc((size_t)N_ATOMS * F * 4);
    unsigned short* x16a = (unsigned short*)alloc((size_t)N_ATOMS * F * 2);
    unsigned short* x16b = (unsigned short*)alloc((size_t)N_ATOMS * F * 2);
    unsigned short* eab  = (unsigned short*)alloc((size_t)N_EDGES * F * 2);
    unsigned short* ybuf = (unsigned short*)alloc((size_t)N_EDGES * F * 2);
    float* filt          = (float*)alloc((size_t)N_EDGES * 4);
    float* agg           = (float*)alloc((size_t)N_ATOMS * F * 4);
    int* cnt             = (int*)alloc((size_t)N_ATOMS * 4);
    int* rowptr          = (int*)alloc((size_t)(N_ATOMS + 1) * 4);
    int* wofs            = (int*)alloc((size_t)N_ATOMS * 4);
    int* i_s             = (int*)alloc((size_t)N_EDGES * 4);
    int* j_s             = (int*)alloc((size_t)N_EDGES * 4);
    int* eperm           = (int*)alloc((size_t)N_EDGES * 4);
    int* bsum            = (int*)alloc(256 * 4);
    float* stats         = (float*)alloc(SLOTS * 128 * 4);
    float* bnp1          = (float*)alloc(128 * 4);
    float* bnp2          = (float*)alloc(128 * 4);
    (void)ws_size; (void)in_sizes; (void)n_in; (void)out_size;

    hipMemsetAsync(cnt, 0, (size_t)N_ATOMS * 4, stream);
    hipMemsetAsync(wofs, 0, (size_t)N_ATOMS * 4, stream);
    k_embed<<<(N_ATOMS * F + 255) / 256, 256, 0, stream>>>(x_types, emb, xa, x16a);
    k_degree<<<(N_EDGES + 255) / 256, 256, 0, stream>>>(idx_i, cnt);
    k_scanA<<<NB_SCAN, 256, 0, stream>>>(cnt, bsum);
    k_scanB<<<1, 256, 0, stream>>>(bsum, rowptr);
    k_scanC<<<NB_SCAN, 256, 0, stream>>>(cnt, bsum, rowptr);
    k_scatter<<<(N_EDGES + 255) / 256, 256, 0, stream>>>(idx_i, idx_j, rowptr, wofs,
                                                         i_s, j_s, eperm);
    k_ea_cvt<<<(N_EDGES * 8 + 255) / 256, 256, 0, stream>>>(ea, eperm, eab);

    float* xcur = xa;
    float* xnxt = xb_f;
    unsigned short* x16cur = x16a;
    unsigned short* x16nxt = x16b;
    for (int l = 0; l < NCONV; ++l) {
        hipMemsetAsync(stats, 0, SLOTS * 128 * 4, stream);
        k_edge_mfma<<<NBLK_MM, 256, 0, stream>>>(
            x16cur, eab, i_s, j_s,
            Wc + (size_t)l * F * Z, Wf + (size_t)l * Z,
            ybuf, filt, stats);
        k_finbn<<<1, 64, 0, stream>>>(stats, bnp1, (float)N_EDGES);
        k_node_agg<<<N_ATOMS / 4, 256, 0, stream>>>(ybuf, filt, rowptr, cnt, bnp1,
                                                    g1 + (size_t)l * F, b1 + (size_t)l * F, agg);
        hipMemsetAsync(stats, 0, SLOTS * 128 * 4, stream);
        k_colstats<<<256, 256, 0, stream>>>(agg, stats);
        k_finbn<<<1, 64, 0, stream>>>(stats, bnp2, (float)N_ATOMS);
        k_node_upd<<<(N_ATOMS * F + 255) / 256, 256, 0, stream>>>(
            agg, bnp2, g2 + (size_t)l * F, b2 + (size_t)l * F, xcur, xnxt, x16nxt);
        float* tf = xcur; xcur = xnxt; xnxt = tf;
        unsigned short* ts = x16cur; x16cur = x16nxt; x16nxt = ts;
    }
    k_head<<<T_TGT / 4, 256, 0, stream>>>(xcur, target, Wfc, bfc, Ws, bs, out);
}